// Round 13
// baseline (4392.543 us; speedup 1.0000x reference)
//
#include <hip/hip_runtime.h>
#include <math.h>

#define BB   128
#define PP   256
#define PIX_ 256
#define DD   512
#define CC   10
#define MTOT (BB*PP)   // 32768
#define NK   1024      // packed complex N for the ff GEMM
#define KA   2048      // A2 / X / Y row length (hi|lo)
#define KB   3072      // Bt3 row length (hi|hi|lo)
#define NSLOT (MTOT/4) // 8192 partial slots (one per norm block, whole batch)

static constexpr float SCALE_F = 0.35355339059327373f; // 8/sqrt(512)
static constexpr float PI_F    = 3.14159265358979323846f;

typedef short bf16x8 __attribute__((ext_vector_type(8)));
typedef float f32x4  __attribute__((ext_vector_type(4)));

__device__ __forceinline__ unsigned short f2bf(float f) {
    union { float f; unsigned u; } v; v.f = f;
    unsigned r = v.u + 0x7FFF + ((v.u >> 16) & 1);   // RNE
    return (unsigned short)(r >> 16);
}
__device__ __forceinline__ float bf2f(unsigned short h) {
    union { unsigned u; float f; } v; v.u = ((unsigned)h) << 16;
    return v.f;
}

// async global->LDS, 16B per lane; LDS dest = wave-uniform base + lane*16B (m97 pattern)
typedef __attribute__((address_space(3))) unsigned lds_u32;
typedef __attribute__((address_space(1))) const unsigned glb_u32;
__device__ __forceinline__ void gl2lds16(const unsigned short* g, short* l) {
    __builtin_amdgcn_global_load_lds((glb_u32*)g, (lds_u32*)l, 16, 0, 0);
}

// ---------------- setup ----------------
__global__ void k_setup(const float* __restrict__ q_rot, const float* __restrict__ k_rot,
                        const float* __restrict__ v_rot,
                        float* __restrict__ freq, float* __restrict__ cd, float* __restrict__ sd,
                        float* __restrict__ cv, float* __restrict__ sv,
                        int* __restrict__ active) {
    int t = threadIdx.x;
    if (t < DD) {
        freq[t] = expf(-(float)t * (9.210340371976184f / 512.0f)); // 10000^(-d/512)
        float dl = q_rot[t] - k_rot[t];
        cd[t] = cosf(dl);       sd[t] = sinf(dl);
        cv[t] = cosf(v_rot[t]); sv[t] = sinf(v_rot[t]);
    }
    if (t == 0) *active = 1;
}

// ---------------- build Bt3[n][0:3072] = [Bhi | Bhi | Blo] (k-major) ----------------
__global__ __launch_bounds__(256) void k_prep3(const float* __restrict__ Fr, const float* __restrict__ Fi,
                                               unsigned short* __restrict__ Bt3) {
    const int n = blockIdx.x;           // 0..1023
    const int t = threadIdx.x;
    unsigned short* row = Bt3 + (size_t)n * KB;
#pragma unroll
    for (int j4 = 0; j4 < 4; j4++) {
        const int j = j4 * 256 + t;
        float v;
        if (n < 512) v = (j < 512) ? Fr[(size_t)j * DD + n] : -Fi[(size_t)(j - 512) * DD + n];
        else         v = (j < 512) ? Fi[(size_t)j * DD + (n - 512)] : Fr[(size_t)(j - 512) * DD + (n - 512)];
        const unsigned short hi = f2bf(v);
        const unsigned short lo = f2bf(v - bf2f(hi));
        row[j] = hi; row[NK + j] = hi; row[2 * NK + j] = lo;
    }
}

#define SCAT4(TILE, V4) do { TILE[lk+0][lrow]=(V4).x; TILE[lk+1][lrow]=(V4).y; \
                             TILE[lk+2][lrow]=(V4).z; TILE[lk+3][lrow]=(V4).w; } while(0)

// ---------------- init: state = tanh(x@Wp^T + bp) * e^{i*p*freq*pi} ---------------- (R2-proven)
__global__ __launch_bounds__(256) void k_init(const float* __restrict__ x,
        const float* __restrict__ Wp, const float* __restrict__ bp,
        const float* __restrict__ freq,
        float* __restrict__ Sr, float* __restrict__ Si) {
    __shared__ float As[16][68];
    __shared__ float Bs[16][68];
    const int bm = blockIdx.y * 64, bn = blockIdx.x * 64;
    const int t = threadIdx.x, tx = t & 15, ty = t >> 4;
    const int lrow = t >> 2, lk = (t & 3) * 4;
    float acc[4][4] = {};
    for (int k0 = 0; k0 < PIX_; k0 += 16) {
        const float4 a4 = *(const float4*)(x  + (size_t)(bm + lrow) * PIX_ + k0 + lk);
        const float4 b4 = *(const float4*)(Wp + (size_t)(bn + lrow) * PIX_ + k0 + lk);
        __syncthreads();
        SCAT4(As, a4);
        SCAT4(Bs, b4);
        __syncthreads();
#pragma unroll
        for (int kk = 0; kk < 16; ++kk) {
            const float4 av = *(const float4*)&As[kk][ty * 4];
            const float4 bv = *(const float4*)&Bs[kk][tx * 4];
            const float a[4] = {av.x, av.y, av.z, av.w};
            const float b[4] = {bv.x, bv.y, bv.z, bv.w};
#pragma unroll
            for (int i = 0; i < 4; i++)
#pragma unroll
                for (int j = 0; j < 4; j++) acc[i][j] = fmaf(a[i], b[j], acc[i][j]);
        }
    }
#pragma unroll
    for (int i = 0; i < 4; i++) {
        const int m = bm + ty * 4 + i;
        const int p = m & 255;
        float4 vr, vi;
        float* pvr = (float*)&vr; float* pvi = (float*)&vi;
#pragma unroll
        for (int j = 0; j < 4; j++) {
            const int d = bn + tx * 4 + j;
            const float mg = tanhf(acc[i][j] + bp[d]);
            const float ph = (float)p * freq[d] * PI_F;
            float sph, cph; sincosf(ph, &sph, &cph);
            pvr[j] = mg * cph; pvi[j] = mg * sph;
        }
        *(float4*)(Sr + (size_t)m * DD + bn + tx * 4) = vr;
        *(float4*)(Si + (size_t)m * DD + bn + tx * 4) = vi;
    }
}

// ---------------- X/Y pack: X=[hi(sr|si)|lo], Y=[hi(krot)|lo] per chunk-row ---------------- (R12-proven)
__global__ __launch_bounds__(256) void k_xy(const float* __restrict__ Sr, const float* __restrict__ Si,
        const float* __restrict__ cd, const float* __restrict__ sd,
        unsigned short* __restrict__ X, unsigned short* __restrict__ Y,
        const int* __restrict__ active) {
    if (*active == 0) return;
    const int r = blockIdx.x, t = threadIdx.x;
    const size_t base = (size_t)r * DD + 2 * t;
    const float2 s_r = *(const float2*)(Sr + base);
    const float2 s_i = *(const float2*)(Si + base);
    const float2 c2  = *(const float2*)(cd + 2 * t);
    const float2 s2  = *(const float2*)(sd + 2 * t);
    unsigned short* xr = X + (size_t)r * KA;
    unsigned short* yr = Y + (size_t)r * KA;
    const float srv[2] = {s_r.x, s_r.y}, siv[2] = {s_i.x, s_i.y};
    const float cv_[2] = {c2.x, c2.y},  sv_[2] = {s2.x, s2.y};
    ushort2 xh_r, xh_i, xl_r, xl_i, yh_r, yh_i, yl_r, yl_i;
    unsigned short* o[8] = {(unsigned short*)&xh_r, (unsigned short*)&xh_i,
                            (unsigned short*)&xl_r, (unsigned short*)&xl_i,
                            (unsigned short*)&yh_r, (unsigned short*)&yh_i,
                            (unsigned short*)&yl_r, (unsigned short*)&yl_i};
#pragma unroll
    for (int e = 0; e < 2; e++) {
        const unsigned short hr = f2bf(srv[e]);
        const unsigned short hi_ = f2bf(siv[e]);
        o[0][e] = hr;  o[2][e] = f2bf(srv[e] - bf2f(hr));
        o[1][e] = hi_; o[3][e] = f2bf(siv[e] - bf2f(hi_));
        const float krr = srv[e] * cv_[e] + siv[e] * sv_[e];
        const float kri = siv[e] * cv_[e] - srv[e] * sv_[e];
        const unsigned short yh1 = f2bf(krr);
        const unsigned short yh2 = f2bf(kri);
        o[4][e] = yh1; o[6][e] = f2bf(krr - bf2f(yh1));
        o[5][e] = yh2; o[7][e] = f2bf(kri - bf2f(yh2));
    }
    *(ushort2*)(xr + 2 * t)        = xh_r;
    *(ushort2*)(xr + 512 + 2 * t)  = xh_i;
    *(ushort2*)(xr + 1024 + 2 * t) = xl_r;
    *(ushort2*)(xr + 1536 + 2 * t) = xl_i;
    *(ushort2*)(yr + 2 * t)        = yh_r;
    *(ushort2*)(yr + 512 + 2 * t)  = yh_i;
    *(ushort2*)(yr + 1024 + 2 * t) = yl_r;
    *(ushort2*)(yr + 1536 + 2 * t) = yl_i;
}

// ---------------- FUSED scores + softmax via split-bf16 MFMA ----------------
// Block = 64 rows x 256 cols (full row), 4 waves x 16 rows, acc 16 x f32x4.
// After K-loop each row lives in one quad's 16 lanes (col = tc*16+lane15) ->
// softmax via 16-lane shfl_xor; writes normalized probs to Asc (fp32).
__global__ __launch_bounds__(256) void k_score_sm(const unsigned short* __restrict__ X,
        const unsigned short* __restrict__ Y,
        float* __restrict__ Asc, const int* __restrict__ active) {
    if (*active == 0) return;
    __shared__ short Al[64][32];    // 4 KB
    __shared__ short Bl[256][32];   // 16 KB
    const int t = threadIdx.x;
    const int w = t >> 6, L = t & 63;
    const int lane15 = L & 15, quad = L >> 4;
    const int bm = blockIdx.x * 64;           // chunk-local row base (same sample: 64 | 256)
    const int yb = (blockIdx.x >> 2) * PP;    // Y row base for this sample
    const int gr = t >> 2, ch = (t & 3) * 8;  // staging row (0..63), 8-short chunk
    short* AlW = &Al[0][0] + w * 512;         // wave-uniform LDS bases (16 rows/wave/issue)
    short* BlW0 = &Bl[0][0]   + w * 512;
    short* BlW1 = &Bl[64][0]  + w * 512;
    short* BlW2 = &Bl[128][0] + w * 512;
    short* BlW3 = &Bl[192][0] + w * 512;
    f32x4 acc[16] = {};
    for (int k0 = 0; k0 < KB; k0 += 32) {
        const int acol = (k0 < 2048) ? k0 : (k0 - 2048);
        const int bcol = (k0 < 1024) ? k0 : (k0 - 1024);
        __syncthreads();
        gl2lds16(X + (size_t)(bm + gr) * KA + acol + ch, AlW);
        gl2lds16(Y + (size_t)(yb + gr) * KA       + bcol + ch, BlW0);
        gl2lds16(Y + (size_t)(yb + 64 + gr) * KA  + bcol + ch, BlW1);
        gl2lds16(Y + (size_t)(yb + 128 + gr) * KA + bcol + ch, BlW2);
        gl2lds16(Y + (size_t)(yb + 192 + gr) * KA + bcol + ch, BlW3);
        __syncthreads();
        const bf16x8 af = *(const bf16x8*)&Al[w * 16 + lane15][quad * 8];
#pragma unroll
        for (int tc = 0; tc < 16; tc++) {
            const bf16x8 bf = *(const bf16x8*)&Bl[tc * 16 + lane15][quad * 8];
            acc[tc] = __builtin_amdgcn_mfma_f32_16x16x32_bf16(af, bf, acc[tc], 0, 0, 0);
        }
    }
    // fused softmax: row = bm + w*16 + quad*4 + r, cols tc*16+lane15 across quad's 16 lanes
#pragma unroll
    for (int r = 0; r < 4; r++) {
        float v[16];
        float m = -1e30f;
#pragma unroll
        for (int tc = 0; tc < 16; tc++) { v[tc] = acc[tc][r] * SCALE_F; m = fmaxf(m, v[tc]); }
        m = fmaxf(m, __shfl_xor(m, 1, 64));
        m = fmaxf(m, __shfl_xor(m, 2, 64));
        m = fmaxf(m, __shfl_xor(m, 4, 64));
        m = fmaxf(m, __shfl_xor(m, 8, 64));
        float s = 0.f;
#pragma unroll
        for (int tc = 0; tc < 16; tc++) { v[tc] = __expf(v[tc] - m); s += v[tc]; }
        s += __shfl_xor(s, 1, 64);
        s += __shfl_xor(s, 2, 64);
        s += __shfl_xor(s, 4, 64);
        s += __shfl_xor(s, 8, 64);
        const float inv = 1.0f / s;
        const size_t row = (size_t)(bm + w * 16 + quad * 4 + r) * PP;
#pragma unroll
        for (int tc = 0; tc < 16; tc++)
            Asc[row + tc * 16 + lane15] = v[tc] * inv;
    }
}

// ---------------- attn_out -> A2 rows [hi(Tr|Ti) | lo(Tr|Ti)] of 2048 bf16 ---------------- (R6-proven)
__global__ __launch_bounds__(256) void k_attnout(const float* __restrict__ A,
        const float* __restrict__ Sr, const float* __restrict__ Si,
        const float* __restrict__ cv, const float* __restrict__ sv,
        unsigned short* __restrict__ A2, const int* __restrict__ active) {
    if (*active == 0) return;
    __shared__ float As[16][68], Br[16][68], Bi[16][68];
    const int b = blockIdx.z;
    const int bm = blockIdx.y * 64, bn = blockIdx.x * 64;
    const int t = threadIdx.x, tx = t & 15, ty = t >> 4;
    const int lrow = t >> 2, lk = (t & 3) * 4;
    const int bkk = t >> 4, bn4 = (t & 15) * 4;
    const float* Ab = A + (size_t)b * PP * PP;
    const float* sr = Sr + (size_t)b * PP * DD;
    const float* si = Si + (size_t)b * PP * DD;
    float accr[4][4] = {}, acci[4][4] = {};
    for (int k0 = 0; k0 < PP; k0 += 16) {
        const float4 a4  = *(const float4*)(Ab + (size_t)(bm + lrow) * PP + k0 + lk);
        const float4 br4 = *(const float4*)(sr + (size_t)(k0 + bkk) * DD + bn + bn4);
        const float4 bi4 = *(const float4*)(si + (size_t)(k0 + bkk) * DD + bn + bn4);
        __syncthreads();
        SCAT4(As, a4);
        *(float4*)&Br[bkk][bn4] = br4;
        *(float4*)&Bi[bkk][bn4] = bi4;
        __syncthreads();
#pragma unroll
        for (int kk = 0; kk < 16; ++kk) {
            const float4 av  = *(const float4*)&As[kk][ty * 4];
            const float4 brv = *(const float4*)&Br[kk][tx * 4];
            const float4 biv = *(const float4*)&Bi[kk][tx * 4];
            const float a[4]   = {av.x, av.y, av.z, av.w};
            const float br_[4] = {brv.x, brv.y, brv.z, brv.w};
            const float bi_[4] = {biv.x, biv.y, biv.z, biv.w};
#pragma unroll
            for (int i = 0; i < 4; i++)
#pragma unroll
                for (int j = 0; j < 4; j++) {
                    accr[i][j] = fmaf(a[i], br_[j], accr[i][j]);
                    acci[i][j] = fmaf(a[i], bi_[j], acci[i][j]);
                }
        }
    }
#pragma unroll
    for (int i = 0; i < 4; i++) {
        const int p = bm + ty * 4 + i;
        ushort4 hrh, hih, hrl, hil;
        unsigned short* p_hrh = (unsigned short*)&hrh;
        unsigned short* p_hih = (unsigned short*)&hih;
        unsigned short* p_hrl = (unsigned short*)&hrl;
        unsigned short* p_hil = (unsigned short*)&hil;
#pragma unroll
        for (int j = 0; j < 4; j++) {
            const int d = bn + tx * 4 + j;
            const float cvd = cv[d], svd = sv[d];
            const float wr = accr[i][j], wi = acci[i][j];
            const float tr = sr[(size_t)p * DD + d] + (wr * cvd - wi * svd);
            const float ti = si[(size_t)p * DD + d] + (wr * svd + wi * cvd);
            const unsigned short rh = f2bf(tr);
            const unsigned short ih = f2bf(ti);
            p_hrh[j] = rh; p_hrl[j] = f2bf(tr - bf2f(rh));
            p_hih[j] = ih; p_hil[j] = f2bf(ti - bf2f(ih));
        }
        const size_t arow = ((size_t)b * PP + p) * KA;
        *(ushort4*)(A2 + arow + bn + tx * 4) = hrh;
        *(ushort4*)(A2 + arow + 512 + bn + tx * 4) = hih;
        *(ushort4*)(A2 + arow + 1024 + bn + tx * 4) = hrl;
        *(ushort4*)(A2 + arow + 1536 + bn + tx * 4) = hil;
    }
}

// ---------------- ff via split-bf16 MFMA, global_load_lds staging ---------------- (R9-proven)
__global__ __launch_bounds__(256) void k_ff_mfma3(const unsigned short* __restrict__ A2,
        const unsigned short* __restrict__ Bt3,
        float* __restrict__ U, const int* __restrict__ active) {
    if (*active == 0) return;
    __shared__ short Al[128][32];
    __shared__ short Bl[128][32];
    const int t = threadIdx.x;
    const int w = t >> 6, L = t & 63;
    const int lane15 = L & 15, quad = L >> 4;
    const int bm = blockIdx.y * 128, bn = blockIdx.x * 128;
    const int gr = t >> 2, ch = (t & 3) * 8;
    short* AlW0 = &Al[0][0] + w * 512;
    short* AlW1 = AlW0 + 64 * 32;
    short* BlW0 = &Bl[0][0] + w * 512;
    short* BlW1 = BlW0 + 64 * 32;
    f32x4 acc[2][8] = {};
    for (int k0 = 0; k0 < KB; k0 += 32) {
        const int acol = (k0 < 2048) ? k0 : (k0 - 2048);
        __syncthreads();
        gl2lds16(A2  + (size_t)(bm + gr) * KA      + acol + ch, AlW0);
        gl2lds16(A2  + (size_t)(bm + 64 + gr) * KA + acol + ch, AlW1);
        gl2lds16(Bt3 + (size_t)(bn + gr) * KB      + k0 + ch,   BlW0);
        gl2lds16(Bt3 + (size_t)(bn + 64 + gr) * KB + k0 + ch,   BlW1);
        __syncthreads();
        bf16x8 bf[8];
#pragma unroll
        for (int tc = 0; tc < 8; tc++)
            bf[tc] = *(const bf16x8*)&Bl[tc * 16 + lane15][quad * 8];
#pragma unroll
        for (int tr = 0; tr < 2; tr++) {
            const bf16x8 af = *(const bf16x8*)&Al[w * 32 + tr * 16 + lane15][quad * 8];
#pragma unroll
            for (int tc = 0; tc < 8; tc++)
                acc[tr][tc] = __builtin_amdgcn_mfma_f32_16x16x32_bf16(af, bf[tc], acc[tr][tc], 0, 0, 0);
        }
    }
#pragma unroll
    for (int tr = 0; tr < 2; tr++)
#pragma unroll
        for (int tc = 0; tc < 8; tc++) {
            const int n = bn + tc * 16 + lane15;
            const int mbase = bm + w * 32 + tr * 16 + quad * 4;
#pragma unroll
            for (int r = 0; r < 4; r++)
                U[(size_t)(mbase + r) * NK + n] = acc[tr][tc][r];
        }
}

// ---------------- complex_norm + commit + per-block partial (NO atomics) ---------------- (R8-proven)
__global__ __launch_bounds__(256) void k_norm(const float* __restrict__ U,
        float* __restrict__ Sr, float* __restrict__ Si,
        float* __restrict__ part, const int* __restrict__ active) {
    if (*active == 0) return;
    __shared__ float red[8];
    const int t = threadIdx.x, rt = t >> 6, L = t & 63;
    const int row = blockIdx.x * 4 + rt;
    const size_t ub = (size_t)row * NK;
    const size_t base = (size_t)row * DD;
    const float4 ur0 = *(const float4*)(U + ub + 4 * L);
    const float4 ur1 = *(const float4*)(U + ub + 256 + 4 * L);
    const float4 ui0 = *(const float4*)(U + ub + 512 + 4 * L);
    const float4 ui1 = *(const float4*)(U + ub + 768 + 4 * L);
    const float4 pr0 = *(const float4*)(Sr + base + 4 * L);
    const float4 pr1 = *(const float4*)(Sr + base + 256 + 4 * L);
    const float4 pi0 = *(const float4*)(Si + base + 4 * L);
    const float4 pi1 = *(const float4*)(Si + base + 256 + 4 * L);
    const float urr[8] = {ur0.x, ur0.y, ur0.z, ur0.w, ur1.x, ur1.y, ur1.z, ur1.w};
    const float uii[8] = {ui0.x, ui0.y, ui0.z, ui0.w, ui1.x, ui1.y, ui1.z, ui1.w};
    float mg[8], msum = 0.f;
#pragma unroll
    for (int e = 0; e < 8; e++) {
        mg[e] = sqrtf(urr[e] * urr[e] + uii[e] * uii[e]);
        msum += mg[e];
    }
#pragma unroll
    for (int off = 32; off; off >>= 1) msum += __shfl_xor(msum, off, 64);
    const float mean = msum * (1.0f / 512.0f);
    float vs = 0.f;
#pragma unroll
    for (int e = 0; e < 8; e++) { const float d = mg[e] - mean; vs += d * d; }
#pragma unroll
    for (int off = 32; off; off >>= 1) vs += __shfl_xor(vs, off, 64);
    const float istd = 1.0f / (sqrtf(vs * (1.0f / 511.0f)) + 1e-5f);
    float nr[8], ni[8];
#pragma unroll
    for (int e = 0; e < 8; e++) {
        const float sc = tanhf((mg[e] - mean) * istd) / (mg[e] + 1e-5f);
        nr[e] = urr[e] * sc; ni[e] = uii[e] * sc;
    }
    const float prr[8] = {pr0.x, pr0.y, pr0.z, pr0.w, pr1.x, pr1.y, pr1.z, pr1.w};
    const float pii[8] = {pi0.x, pi0.y, pi0.z, pi0.w, pi1.x, pi1.y, pi1.z, pi1.w};
    float dd = 0.f, nn = 0.f;
#pragma unroll
    for (int e = 0; e < 8; e++) {
        const float dr = nr[e] - prr[e], di = ni[e] - pii[e];
        dd += dr * dr + di * di;
        nn += nr[e] * nr[e] + ni[e] * ni[e];
    }
    *(float4*)(Sr + base + 4 * L)       = make_float4(nr[0], nr[1], nr[2], nr[3]);
    *(float4*)(Sr + base + 256 + 4 * L) = make_float4(nr[4], nr[5], nr[6], nr[7]);
    *(float4*)(Si + base + 4 * L)       = make_float4(ni[0], ni[1], ni[2], ni[3]);
    *(float4*)(Si + base + 256 + 4 * L) = make_float4(ni[4], ni[5], ni[6], ni[7]);
#pragma unroll
    for (int off = 32; off; off >>= 1) {
        dd += __shfl_xor(dd, off, 64);
        nn += __shfl_xor(nn, off, 64);
    }
    if (L == 0) { red[rt] = dd; red[4 + rt] = nn; }
    __syncthreads();
    if (t == 0)
        *(float2*)(part + 2 * blockIdx.x) =
            make_float2(red[0] + red[1] + red[2] + red[3],
                        red[4] + red[5] + red[6] + red[7]);
}

// ---------------- convergence flag: reduce all NSLOT partials ----------------
__global__ __launch_bounds__(256) void k_flag(const float* __restrict__ part, int* __restrict__ active) {
    __shared__ float red[8];
    const int t = threadIdx.x, rt = t >> 6, L = t & 63;
    float dd = 0.f, nn = 0.f;
    for (int i = t; i < NSLOT; i += 256) {
        const float2 p = *(const float2*)(part + 2 * i);
        dd += p.x; nn += p.y;
    }
#pragma unroll
    for (int off = 32; off; off >>= 1) {
        dd += __shfl_xor(dd, off, 64);
        nn += __shfl_xor(nn, off, 64);
    }
    if (L == 0) { red[rt] = dd; red[4 + rt] = nn; }
    __syncthreads();
    if (t == 0) {
        const float d = red[0] + red[1] + red[2] + red[3];
        const float n = red[4] + red[5] + red[6] + red[7];
        const float diff = sqrtf(d) / (sqrtf(n) + 1e-8f);
        const int a = *active;
        *active = (a && (diff >= 1e-3f)) ? 1 : 0;
    }
}

// ---------------- mean over P ----------------
__global__ __launch_bounds__(256) void k_pool(const float* __restrict__ Sr, const float* __restrict__ Si,
        float* __restrict__ Pr, float* __restrict__ Pi) {
    const int gid = blockIdx.x * 256 + threadIdx.x;
    const int b = gid >> 9, d = gid & 511;
    const size_t base = (size_t)b * PP * DD + d;
    float sr = 0.f, si = 0.f;
    for (int p = 0; p < PP; p++) {
        sr += Sr[base + (size_t)p * DD];
        si += Si[base + (size_t)p * DD];
    }
    Pr[gid] = sr * (1.0f / 256.0f);
    Pi[gid] = si * (1.0f / 256.0f);
}

// ---------------- logits ----------------
__global__ __launch_bounds__(64) void k_logits(const float* __restrict__ Pr, const float* __restrict__ Pi,
        const float* __restrict__ Wr, const float* __restrict__ br,
        const float* __restrict__ Wi, const float* __restrict__ bi,
        float* __restrict__ out) {
    const int b = blockIdx.x;
    const int lane = threadIdx.x;
    for (int c = 0; c < CC; c++) {
        float acc = 0.f;
#pragma unroll
        for (int k = 0; k < 8; k++) {
            const int d = lane + 64 * k;
            acc += Pr[b * DD + d] * Wr[c * DD + d] + Pi[b * DD + d] * Wi[c * DD + d];
        }
#pragma unroll
        for (int off = 32; off; off >>= 1) acc += __shfl_xor(acc, off, 64);
        if (lane == 0) out[b * CC + c] = acc + br[c] + bi[c];
    }
}

extern "C" void kernel_launch(void* const* d_in, const int* in_sizes, int n_in,
                              void* d_out, int out_size, void* d_ws, size_t ws_size,
                              hipStream_t stream) {
    const float* x     = (const float*)d_in[0];
    const float* Wp    = (const float*)d_in[1];
    const float* bp    = (const float*)d_in[2];
    const float* q_rot = (const float*)d_in[3];
    const float* k_rot = (const float*)d_in[4];
    const float* v_rot = (const float*)d_in[5];
    const float* ffr   = (const float*)d_in[6];
    const float* ffi   = (const float*)d_in[7];
    const float* Wr    = (const float*)d_in[8];
    const float* br    = (const float*)d_in[9];
    const float* Wi    = (const float*)d_in[10];
    const float* bi    = (const float*)d_in[11];
    float* out = (float*)d_out;

    float* ws = (float*)d_ws;
    const size_t plane = (size_t)MTOT * DD;      // 16,777,216 floats
    const size_t sline = (size_t)PP * DD;

    float* freq = ws;                  // 512
    float* cd   = freq + DD;
    float* sd   = cd + DD;
    float* cv   = sd + DD;
    float* sv   = cv + DD;
    int*   active = (int*)(sv + DD);   // 1
    float* Pr = ws + 4096;             // 65536
    float* Pi = Pr + (size_t)BB * DD;  // 65536
    float* part = Pi + (size_t)BB * DD;        // 2*NSLOT = 16384 floats
    float* Sr = part + 2 * NSLOT;              // fp32 state (128 MiB)
    float* Si = Sr + plane;
    unsigned short* Bt3 = (unsigned short*)(Si + plane);  // 1024x3072 bf16 (6 MB)
    float* chunkbase = Si + plane + (size_t)NK * KB / 2;

    const size_t fixed_f = (4096 + 2 * (size_t)BB * DD + 2 * NSLOT) + 2 * plane + (size_t)NK * KB / 2;
    // per-sample: U (PP*NK f32) + A2/X overlay (PP*KA bf16) + Y (PP*KA bf16) = 786432 floats = 3 MB
    const size_t perC_f = (size_t)PP * NK + (size_t)PP * KA;   // 786432

    // R9-proven power-of-2 chunking.
    int C = BB;
    while (C > 1 && (fixed_f + (size_t)C * perC_f) * 4ull > ws_size) C >>= 1;

    float* U = chunkbase;                                   // C x 256 x 1024 fp32
    float* Asc = U;                                         // overlay; dead before U written
    unsigned short* A2 = (unsigned short*)(U + (size_t)C * PP * NK);  // C x 256 x 2048 bf16
    unsigned short* X  = A2;                                // overlay: X dead before attnout writes A2
    unsigned short* Y  = A2 + (size_t)C * PP * KA;          // C x 256 x 2048 bf16

    k_setup<<<1, 512, 0, stream>>>(q_rot, k_rot, v_rot, freq, cd, sd, cv, sv, active);
    k_prep3<<<NK, 256, 0, stream>>>(ffr, ffi, Bt3);
    k_init<<<dim3(DD / 64, MTOT / 64), 256, 0, stream>>>(x, Wp, bp, freq, Sr, Si);

    for (int it = 0; it < 4; ++it) {
        for (int c0 = 0; c0 < BB; c0 += C) {
            float* Sr_c = Sr + (size_t)c0 * sline;
            float* Si_c = Si + (size_t)c0 * sline;
            float* part_c = part + (size_t)c0 * (PP / 4) * 2;
            k_xy<<<C * PP, 256, 0, stream>>>(Sr_c, Si_c, cd, sd, X, Y, active);
            k_score_sm<<<C * PP / 64, 256, 0, stream>>>(X, Y, Asc, active);
            k_attnout<<<dim3(DD / 64, PP / 64, C), 256, 0, stream>>>(Asc, Sr_c, Si_c, cv, sv, A2, active);
            k_ff_mfma3<<<dim3(NK / 128, C * 2), 256, 0, stream>>>(A2, Bt3, U, active);
            k_norm<<<C * (PP / 4), 256, 0, stream>>>(U, Sr_c, Si_c, part_c, active);
        }
        k_flag<<<1, 256, 0, stream>>>(part, active);
    }

    k_pool<<<BB * DD / 256, 256, 0, stream>>>(Sr, Si, Pr, Pi);
    k_logits<<<BB, 64, 0, stream>>>(Pr, Pi, Wr, br, Wi, bi, out);
}

// Round 14
// 4026.983 us; speedup vs baseline: 1.0908x; 1.0908x over previous
//
#include <hip/hip_runtime.h>
#include <math.h>

#define BB   128
#define PP   256
#define PIX_ 256
#define DD   512
#define CC   10
#define MTOT (BB*PP)   // 32768
#define NK   1024      // packed complex N for the ff GEMM
#define KA   2048      // A2 / X / Y row length (hi|lo)
#define KB   3072      // Bt3 row length (hi|hi|lo)
#define NSLOT (MTOT/4) // 8192 partial slots (one per norm block, whole batch)

static constexpr float SCALE_F = 0.35355339059327373f; // 8/sqrt(512)
static constexpr float PI_F    = 3.14159265358979323846f;

typedef short bf16x8 __attribute__((ext_vector_type(8)));
typedef float f32x4  __attribute__((ext_vector_type(4)));

__device__ __forceinline__ unsigned short f2bf(float f) {
    union { float f; unsigned u; } v; v.f = f;
    unsigned r = v.u + 0x7FFF + ((v.u >> 16) & 1);   // RNE
    return (unsigned short)(r >> 16);
}
__device__ __forceinline__ float bf2f(unsigned short h) {
    union { unsigned u; float f; } v; v.u = ((unsigned)h) << 16;
    return v.f;
}

// async global->LDS, 16B per lane; LDS dest = wave-uniform base + lane*16B (m97 pattern)
typedef __attribute__((address_space(3))) unsigned lds_u32;
typedef __attribute__((address_space(1))) const unsigned glb_u32;
__device__ __forceinline__ void gl2lds16(const unsigned short* g, short* l) {
    __builtin_amdgcn_global_load_lds((glb_u32*)g, (lds_u32*)l, 16, 0, 0);
}

// ---------------- setup ----------------
__global__ void k_setup(const float* __restrict__ q_rot, const float* __restrict__ k_rot,
                        const float* __restrict__ v_rot,
                        float* __restrict__ freq, float* __restrict__ cd, float* __restrict__ sd,
                        float* __restrict__ cv, float* __restrict__ sv,
                        int* __restrict__ active) {
    int t = threadIdx.x;
    if (t < DD) {
        freq[t] = expf(-(float)t * (9.210340371976184f / 512.0f)); // 10000^(-d/512)
        float dl = q_rot[t] - k_rot[t];
        cd[t] = cosf(dl);       sd[t] = sinf(dl);
        cv[t] = cosf(v_rot[t]); sv[t] = sinf(v_rot[t]);
    }
    if (t == 0) *active = 1;
}

// ---------------- build Bt3[n][0:3072] = [Bhi | Bhi | Blo] (k-major) ----------------
__global__ __launch_bounds__(256) void k_prep3(const float* __restrict__ Fr, const float* __restrict__ Fi,
                                               unsigned short* __restrict__ Bt3) {
    const int n = blockIdx.x;           // 0..1023
    const int t = threadIdx.x;
    unsigned short* row = Bt3 + (size_t)n * KB;
#pragma unroll
    for (int j4 = 0; j4 < 4; j4++) {
        const int j = j4 * 256 + t;
        float v;
        if (n < 512) v = (j < 512) ? Fr[(size_t)j * DD + n] : -Fi[(size_t)(j - 512) * DD + n];
        else         v = (j < 512) ? Fi[(size_t)j * DD + (n - 512)] : Fr[(size_t)(j - 512) * DD + (n - 512)];
        const unsigned short hi = f2bf(v);
        const unsigned short lo = f2bf(v - bf2f(hi));
        row[j] = hi; row[NK + j] = hi; row[2 * NK + j] = lo;
    }
}

#define SCAT4(TILE, V4) do { TILE[lk+0][lrow]=(V4).x; TILE[lk+1][lrow]=(V4).y; \
                             TILE[lk+2][lrow]=(V4).z; TILE[lk+3][lrow]=(V4).w; } while(0)

// ---------------- init: state = tanh(x@Wp^T + bp) * e^{i*p*freq*pi} ---------------- (R2-proven)
__global__ __launch_bounds__(256) void k_init(const float* __restrict__ x,
        const float* __restrict__ Wp, const float* __restrict__ bp,
        const float* __restrict__ freq,
        float* __restrict__ Sr, float* __restrict__ Si) {
    __shared__ float As[16][68];
    __shared__ float Bs[16][68];
    const int bm = blockIdx.y * 64, bn = blockIdx.x * 64;
    const int t = threadIdx.x, tx = t & 15, ty = t >> 4;
    const int lrow = t >> 2, lk = (t & 3) * 4;
    float acc[4][4] = {};
    for (int k0 = 0; k0 < PIX_; k0 += 16) {
        const float4 a4 = *(const float4*)(x  + (size_t)(bm + lrow) * PIX_ + k0 + lk);
        const float4 b4 = *(const float4*)(Wp + (size_t)(bn + lrow) * PIX_ + k0 + lk);
        __syncthreads();
        SCAT4(As, a4);
        SCAT4(Bs, b4);
        __syncthreads();
#pragma unroll
        for (int kk = 0; kk < 16; ++kk) {
            const float4 av = *(const float4*)&As[kk][ty * 4];
            const float4 bv = *(const float4*)&Bs[kk][tx * 4];
            const float a[4] = {av.x, av.y, av.z, av.w};
            const float b[4] = {bv.x, bv.y, bv.z, bv.w};
#pragma unroll
            for (int i = 0; i < 4; i++)
#pragma unroll
                for (int j = 0; j < 4; j++) acc[i][j] = fmaf(a[i], b[j], acc[i][j]);
        }
    }
#pragma unroll
    for (int i = 0; i < 4; i++) {
        const int m = bm + ty * 4 + i;
        const int p = m & 255;
        float4 vr, vi;
        float* pvr = (float*)&vr; float* pvi = (float*)&vi;
#pragma unroll
        for (int j = 0; j < 4; j++) {
            const int d = bn + tx * 4 + j;
            const float mg = tanhf(acc[i][j] + bp[d]);
            const float ph = (float)p * freq[d] * PI_F;
            float sph, cph; sincosf(ph, &sph, &cph);
            pvr[j] = mg * cph; pvi[j] = mg * sph;
        }
        *(float4*)(Sr + (size_t)m * DD + bn + tx * 4) = vr;
        *(float4*)(Si + (size_t)m * DD + bn + tx * 4) = vi;
    }
}

// ---------------- X/Y pack: X=[hi(sr|si)|lo], Y=[hi(krot)|lo] per chunk-row ---------------- (R12-proven)
__global__ __launch_bounds__(256) void k_xy(const float* __restrict__ Sr, const float* __restrict__ Si,
        const float* __restrict__ cd, const float* __restrict__ sd,
        unsigned short* __restrict__ X, unsigned short* __restrict__ Y,
        const int* __restrict__ active) {
    if (*active == 0) return;
    const int r = blockIdx.x, t = threadIdx.x;
    const size_t base = (size_t)r * DD + 2 * t;
    const float2 s_r = *(const float2*)(Sr + base);
    const float2 s_i = *(const float2*)(Si + base);
    const float2 c2  = *(const float2*)(cd + 2 * t);
    const float2 s2  = *(const float2*)(sd + 2 * t);
    unsigned short* xr = X + (size_t)r * KA;
    unsigned short* yr = Y + (size_t)r * KA;
    const float srv[2] = {s_r.x, s_r.y}, siv[2] = {s_i.x, s_i.y};
    const float cv_[2] = {c2.x, c2.y},  sv_[2] = {s2.x, s2.y};
    ushort2 xh_r, xh_i, xl_r, xl_i, yh_r, yh_i, yl_r, yl_i;
    unsigned short* o[8] = {(unsigned short*)&xh_r, (unsigned short*)&xh_i,
                            (unsigned short*)&xl_r, (unsigned short*)&xl_i,
                            (unsigned short*)&yh_r, (unsigned short*)&yh_i,
                            (unsigned short*)&yl_r, (unsigned short*)&yl_i};
#pragma unroll
    for (int e = 0; e < 2; e++) {
        const unsigned short hr = f2bf(srv[e]);
        const unsigned short hi_ = f2bf(siv[e]);
        o[0][e] = hr;  o[2][e] = f2bf(srv[e] - bf2f(hr));
        o[1][e] = hi_; o[3][e] = f2bf(siv[e] - bf2f(hi_));
        const float krr = srv[e] * cv_[e] + siv[e] * sv_[e];
        const float kri = siv[e] * cv_[e] - srv[e] * sv_[e];
        const unsigned short yh1 = f2bf(krr);
        const unsigned short yh2 = f2bf(kri);
        o[4][e] = yh1; o[6][e] = f2bf(krr - bf2f(yh1));
        o[5][e] = yh2; o[7][e] = f2bf(kri - bf2f(yh2));
    }
    *(ushort2*)(xr + 2 * t)        = xh_r;
    *(ushort2*)(xr + 512 + 2 * t)  = xh_i;
    *(ushort2*)(xr + 1024 + 2 * t) = xl_r;
    *(ushort2*)(xr + 1536 + 2 * t) = xl_i;
    *(ushort2*)(yr + 2 * t)        = yh_r;
    *(ushort2*)(yr + 512 + 2 * t)  = yh_i;
    *(ushort2*)(yr + 1024 + 2 * t) = yl_r;
    *(ushort2*)(yr + 1536 + 2 * t) = yl_i;
}

// ---------------- scores via split-bf16 MFMA: S = scale*(X @ Y^T), 3-term K=3072 ---------------- (R12-proven)
__global__ __launch_bounds__(256) void k_score_mfma(const unsigned short* __restrict__ X,
        const unsigned short* __restrict__ Y,
        float* __restrict__ Asc, const int* __restrict__ active) {
    if (*active == 0) return;
    __shared__ short Al[128][32];
    __shared__ short Bl[128][32];
    const int t = threadIdx.x;
    const int w = t >> 6, L = t & 63;
    const int lane15 = L & 15, quad = L >> 4;
    const int bm = blockIdx.y * 128;
    const int bnG = (((int)blockIdx.y >> 1) * 2 + (int)blockIdx.x) * 128; // Y rows, same sample
    const int qb = blockIdx.x * 128;                                     // q-col base in sample
    const int gr = t >> 2, ch = (t & 3) * 8;
    short* AlW0 = &Al[0][0] + w * 512;
    short* AlW1 = AlW0 + 64 * 32;
    short* BlW0 = &Bl[0][0] + w * 512;
    short* BlW1 = BlW0 + 64 * 32;
    f32x4 acc[2][8] = {};
    for (int k0 = 0; k0 < KB; k0 += 32) {
        const int acol = (k0 < 2048) ? k0 : (k0 - 2048);
        const int bcol = (k0 < 1024) ? k0 : (k0 - 1024);
        __syncthreads();
        gl2lds16(X + (size_t)(bm + gr) * KA      + acol + ch, AlW0);
        gl2lds16(X + (size_t)(bm + 64 + gr) * KA + acol + ch, AlW1);
        gl2lds16(Y + (size_t)(bnG + gr) * KA      + bcol + ch, BlW0);
        gl2lds16(Y + (size_t)(bnG + 64 + gr) * KA + bcol + ch, BlW1);
        __syncthreads();
        bf16x8 bf[8];
#pragma unroll
        for (int tc = 0; tc < 8; tc++)
            bf[tc] = *(const bf16x8*)&Bl[tc * 16 + lane15][quad * 8];
#pragma unroll
        for (int tr = 0; tr < 2; tr++) {
            const bf16x8 af = *(const bf16x8*)&Al[w * 32 + tr * 16 + lane15][quad * 8];
#pragma unroll
            for (int tc = 0; tc < 8; tc++)
                acc[tr][tc] = __builtin_amdgcn_mfma_f32_16x16x32_bf16(af, bf[tc], acc[tr][tc], 0, 0, 0);
        }
    }
#pragma unroll
    for (int tr = 0; tr < 2; tr++)
#pragma unroll
        for (int tc = 0; tc < 8; tc++) {
            const int q = qb + tc * 16 + lane15;
            const int mbase = bm + w * 32 + tr * 16 + quad * 4;
#pragma unroll
            for (int r = 0; r < 4; r++)
                Asc[(size_t)(mbase + r) * PP + q] = acc[tr][tc][r] * SCALE_F;
        }
}

// ---------------- softmax over rows of length 256, one wave per row ---------------- (R5-proven)
__global__ __launch_bounds__(256) void k_softmax(float* __restrict__ A, const int* __restrict__ active) {
    if (*active == 0) return;
    const int row = blockIdx.x * 4 + (threadIdx.x >> 6);
    const int lane = threadIdx.x & 63;
    float* a = A + (size_t)row * PP;
    float v[4];
#pragma unroll
    for (int k = 0; k < 4; k++) v[k] = a[lane + 64 * k];
    float m = fmaxf(fmaxf(v[0], v[1]), fmaxf(v[2], v[3]));
#pragma unroll
    for (int off = 32; off; off >>= 1) m = fmaxf(m, __shfl_xor(m, off, 64));
    float s = 0.f;
#pragma unroll
    for (int k = 0; k < 4; k++) { v[k] = __expf(v[k] - m); s += v[k]; }
#pragma unroll
    for (int off = 32; off; off >>= 1) s += __shfl_xor(s, off, 64);
    const float inv = 1.0f / s;
#pragma unroll
    for (int k = 0; k < 4; k++) a[lane + 64 * k] = v[k] * inv;
}

// ---------------- attn_out -> A2 rows [hi(Tr|Ti) | lo(Tr|Ti)] of 2048 bf16 ---------------- (R6-proven)
__global__ __launch_bounds__(256) void k_attnout(const float* __restrict__ A,
        const float* __restrict__ Sr, const float* __restrict__ Si,
        const float* __restrict__ cv, const float* __restrict__ sv,
        unsigned short* __restrict__ A2, const int* __restrict__ active) {
    if (*active == 0) return;
    __shared__ float As[16][68], Br[16][68], Bi[16][68];
    const int b = blockIdx.z;
    const int bm = blockIdx.y * 64, bn = blockIdx.x * 64;
    const int t = threadIdx.x, tx = t & 15, ty = t >> 4;
    const int lrow = t >> 2, lk = (t & 3) * 4;
    const int bkk = t >> 4, bn4 = (t & 15) * 4;
    const float* Ab = A + (size_t)b * PP * PP;
    const float* sr = Sr + (size_t)b * PP * DD;
    const float* si = Si + (size_t)b * PP * DD;
    float accr[4][4] = {}, acci[4][4] = {};
    for (int k0 = 0; k0 < PP; k0 += 16) {
        const float4 a4  = *(const float4*)(Ab + (size_t)(bm + lrow) * PP + k0 + lk);
        const float4 br4 = *(const float4*)(sr + (size_t)(k0 + bkk) * DD + bn + bn4);
        const float4 bi4 = *(const float4*)(si + (size_t)(k0 + bkk) * DD + bn + bn4);
        __syncthreads();
        SCAT4(As, a4);
        *(float4*)&Br[bkk][bn4] = br4;
        *(float4*)&Bi[bkk][bn4] = bi4;
        __syncthreads();
#pragma unroll
        for (int kk = 0; kk < 16; ++kk) {
            const float4 av  = *(const float4*)&As[kk][ty * 4];
            const float4 brv = *(const float4*)&Br[kk][tx * 4];
            const float4 biv = *(const float4*)&Bi[kk][tx * 4];
            const float a[4]   = {av.x, av.y, av.z, av.w};
            const float br_[4] = {brv.x, brv.y, brv.z, brv.w};
            const float bi_[4] = {biv.x, biv.y, biv.z, biv.w};
#pragma unroll
            for (int i = 0; i < 4; i++)
#pragma unroll
                for (int j = 0; j < 4; j++) {
                    accr[i][j] = fmaf(a[i], br_[j], accr[i][j]);
                    acci[i][j] = fmaf(a[i], bi_[j], acci[i][j]);
                }
        }
    }
#pragma unroll
    for (int i = 0; i < 4; i++) {
        const int p = bm + ty * 4 + i;
        ushort4 hrh, hih, hrl, hil;
        unsigned short* p_hrh = (unsigned short*)&hrh;
        unsigned short* p_hih = (unsigned short*)&hih;
        unsigned short* p_hrl = (unsigned short*)&hrl;
        unsigned short* p_hil = (unsigned short*)&hil;
#pragma unroll
        for (int j = 0; j < 4; j++) {
            const int d = bn + tx * 4 + j;
            const float cvd = cv[d], svd = sv[d];
            const float wr = accr[i][j], wi = acci[i][j];
            const float tr = sr[(size_t)p * DD + d] + (wr * cvd - wi * svd);
            const float ti = si[(size_t)p * DD + d] + (wr * svd + wi * cvd);
            const unsigned short rh = f2bf(tr);
            const unsigned short ih = f2bf(ti);
            p_hrh[j] = rh; p_hrl[j] = f2bf(tr - bf2f(rh));
            p_hih[j] = ih; p_hil[j] = f2bf(ti - bf2f(ih));
        }
        const size_t arow = ((size_t)b * PP + p) * KA;
        *(ushort4*)(A2 + arow + bn + tx * 4) = hrh;
        *(ushort4*)(A2 + arow + 512 + bn + tx * 4) = hih;
        *(ushort4*)(A2 + arow + 1024 + bn + tx * 4) = hrl;
        *(ushort4*)(A2 + arow + 1536 + bn + tx * 4) = hil;
    }
}

// ---------------- ff via split-bf16 MFMA, global_load_lds staging ---------------- (R9-proven)
__global__ __launch_bounds__(256) void k_ff_mfma3(const unsigned short* __restrict__ A2,
        const unsigned short* __restrict__ Bt3,
        float* __restrict__ U, const int* __restrict__ active) {
    if (*active == 0) return;
    __shared__ short Al[128][32];
    __shared__ short Bl[128][32];
    const int t = threadIdx.x;
    const int w = t >> 6, L = t & 63;
    const int lane15 = L & 15, quad = L >> 4;
    const int bm = blockIdx.y * 128, bn = blockIdx.x * 128;
    const int gr = t >> 2, ch = (t & 3) * 8;
    short* AlW0 = &Al[0][0] + w * 512;
    short* AlW1 = AlW0 + 64 * 32;
    short* BlW0 = &Bl[0][0] + w * 512;
    short* BlW1 = BlW0 + 64 * 32;
    f32x4 acc[2][8] = {};
    for (int k0 = 0; k0 < KB; k0 += 32) {
        const int acol = (k0 < 2048) ? k0 : (k0 - 2048);
        __syncthreads();
        gl2lds16(A2  + (size_t)(bm + gr) * KA      + acol + ch, AlW0);
        gl2lds16(A2  + (size_t)(bm + 64 + gr) * KA + acol + ch, AlW1);
        gl2lds16(Bt3 + (size_t)(bn + gr) * KB      + k0 + ch,   BlW0);
        gl2lds16(Bt3 + (size_t)(bn + 64 + gr) * KB + k0 + ch,   BlW1);
        __syncthreads();
        bf16x8 bf[8];
#pragma unroll
        for (int tc = 0; tc < 8; tc++)
            bf[tc] = *(const bf16x8*)&Bl[tc * 16 + lane15][quad * 8];
#pragma unroll
        for (int tr = 0; tr < 2; tr++) {
            const bf16x8 af = *(const bf16x8*)&Al[w * 32 + tr * 16 + lane15][quad * 8];
#pragma unroll
            for (int tc = 0; tc < 8; tc++)
                acc[tr][tc] = __builtin_amdgcn_mfma_f32_16x16x32_bf16(af, bf[tc], acc[tr][tc], 0, 0, 0);
        }
    }
#pragma unroll
    for (int tr = 0; tr < 2; tr++)
#pragma unroll
        for (int tc = 0; tc < 8; tc++) {
            const int n = bn + tc * 16 + lane15;
            const int mbase = bm + w * 32 + tr * 16 + quad * 4;
#pragma unroll
            for (int r = 0; r < 4; r++)
                U[(size_t)(mbase + r) * NK + n] = acc[tr][tc][r];
        }
}

// ---------------- complex_norm + commit + per-block partial (NO atomics) ---------------- (R8-proven)
__global__ __launch_bounds__(256) void k_norm(const float* __restrict__ U,
        float* __restrict__ Sr, float* __restrict__ Si,
        float* __restrict__ part, const int* __restrict__ active) {
    if (*active == 0) return;
    __shared__ float red[8];
    const int t = threadIdx.x, rt = t >> 6, L = t & 63;
    const int row = blockIdx.x * 4 + rt;
    const size_t ub = (size_t)row * NK;
    const size_t base = (size_t)row * DD;
    const float4 ur0 = *(const float4*)(U + ub + 4 * L);
    const float4 ur1 = *(const float4*)(U + ub + 256 + 4 * L);
    const float4 ui0 = *(const float4*)(U + ub + 512 + 4 * L);
    const float4 ui1 = *(const float4*)(U + ub + 768 + 4 * L);
    const float4 pr0 = *(const float4*)(Sr + base + 4 * L);
    const float4 pr1 = *(const float4*)(Sr + base + 256 + 4 * L);
    const float4 pi0 = *(const float4*)(Si + base + 4 * L);
    const float4 pi1 = *(const float4*)(Si + base + 256 + 4 * L);
    const float urr[8] = {ur0.x, ur0.y, ur0.z, ur0.w, ur1.x, ur1.y, ur1.z, ur1.w};
    const float uii[8] = {ui0.x, ui0.y, ui0.z, ui0.w, ui1.x, ui1.y, ui1.z, ui1.w};
    float mg[8], msum = 0.f;
#pragma unroll
    for (int e = 0; e < 8; e++) {
        mg[e] = sqrtf(urr[e] * urr[e] + uii[e] * uii[e]);
        msum += mg[e];
    }
#pragma unroll
    for (int off = 32; off; off >>= 1) msum += __shfl_xor(msum, off, 64);
    const float mean = msum * (1.0f / 512.0f);
    float vs = 0.f;
#pragma unroll
    for (int e = 0; e < 8; e++) { const float d = mg[e] - mean; vs += d * d; }
#pragma unroll
    for (int off = 32; off; off >>= 1) vs += __shfl_xor(vs, off, 64);
    const float istd = 1.0f / (sqrtf(vs * (1.0f / 511.0f)) + 1e-5f);
    float nr[8], ni[8];
#pragma unroll
    for (int e = 0; e < 8; e++) {
        const float sc = tanhf((mg[e] - mean) * istd) / (mg[e] + 1e-5f);
        nr[e] = urr[e] * sc; ni[e] = uii[e] * sc;
    }
    const float prr[8] = {pr0.x, pr0.y, pr0.z, pr0.w, pr1.x, pr1.y, pr1.z, pr1.w};
    const float pii[8] = {pi0.x, pi0.y, pi0.z, pi0.w, pi1.x, pi1.y, pi1.z, pi1.w};
    float dd = 0.f, nn = 0.f;
#pragma unroll
    for (int e = 0; e < 8; e++) {
        const float dr = nr[e] - prr[e], di = ni[e] - pii[e];
        dd += dr * dr + di * di;
        nn += nr[e] * nr[e] + ni[e] * ni[e];
    }
    *(float4*)(Sr + base + 4 * L)       = make_float4(nr[0], nr[1], nr[2], nr[3]);
    *(float4*)(Sr + base + 256 + 4 * L) = make_float4(nr[4], nr[5], nr[6], nr[7]);
    *(float4*)(Si + base + 4 * L)       = make_float4(ni[0], ni[1], ni[2], ni[3]);
    *(float4*)(Si + base + 256 + 4 * L) = make_float4(ni[4], ni[5], ni[6], ni[7]);
#pragma unroll
    for (int off = 32; off; off >>= 1) {
        dd += __shfl_xor(dd, off, 64);
        nn += __shfl_xor(nn, off, 64);
    }
    if (L == 0) { red[rt] = dd; red[4 + rt] = nn; }
    __syncthreads();
    if (t == 0)
        *(float2*)(part + 2 * blockIdx.x) =
            make_float2(red[0] + red[1] + red[2] + red[3],
                        red[4] + red[5] + red[6] + red[7]);
}

// ---------------- convergence flag: reduce all NSLOT partials ----------------
__global__ __launch_bounds__(256) void k_flag(const float* __restrict__ part, int* __restrict__ active) {
    __shared__ float red[8];
    const int t = threadIdx.x, rt = t >> 6, L = t & 63;
    float dd = 0.f, nn = 0.f;
    for (int i = t; i < NSLOT; i += 256) {
        const float2 p = *(const float2*)(part + 2 * i);
        dd += p.x; nn += p.y;
    }
#pragma unroll
    for (int off = 32; off; off >>= 1) {
        dd += __shfl_xor(dd, off, 64);
        nn += __shfl_xor(nn, off, 64);
    }
    if (L == 0) { red[rt] = dd; red[4 + rt] = nn; }
    __syncthreads();
    if (t == 0) {
        const float d = red[0] + red[1] + red[2] + red[3];
        const float n = red[4] + red[5] + red[6] + red[7];
        const float diff = sqrtf(d) / (sqrtf(n) + 1e-8f);
        const int a = *active;
        *active = (a && (diff >= 1e-3f)) ? 1 : 0;
    }
}

// ---------------- mean over P ----------------
__global__ __launch_bounds__(256) void k_pool(const float* __restrict__ Sr, const float* __restrict__ Si,
        float* __restrict__ Pr, float* __restrict__ Pi) {
    const int gid = blockIdx.x * 256 + threadIdx.x;
    const int b = gid >> 9, d = gid & 511;
    const size_t base = (size_t)b * PP * DD + d;
    float sr = 0.f, si = 0.f;
    for (int p = 0; p < PP; p++) {
        sr += Sr[base + (size_t)p * DD];
        si += Si[base + (size_t)p * DD];
    }
    Pr[gid] = sr * (1.0f / 256.0f);
    Pi[gid] = si * (1.0f / 256.0f);
}

// ---------------- logits ----------------
__global__ __launch_bounds__(64) void k_logits(const float* __restrict__ Pr, const float* __restrict__ Pi,
        const float* __restrict__ Wr, const float* __restrict__ br,
        const float* __restrict__ Wi, const float* __restrict__ bi,
        float* __restrict__ out) {
    const int b = blockIdx.x;
    const int lane = threadIdx.x;
    for (int c = 0; c < CC; c++) {
        float acc = 0.f;
#pragma unroll
        for (int k = 0; k < 8; k++) {
            const int d = lane + 64 * k;
            acc += Pr[b * DD + d] * Wr[c * DD + d] + Pi[b * DD + d] * Wi[c * DD + d];
        }
#pragma unroll
        for (int off = 32; off; off >>= 1) acc += __shfl_xor(acc, off, 64);
        if (lane == 0) out[b * CC + c] = acc + br[c] + bi[c];
    }
}

extern "C" void kernel_launch(void* const* d_in, const int* in_sizes, int n_in,
                              void* d_out, int out_size, void* d_ws, size_t ws_size,
                              hipStream_t stream) {
    const float* x     = (const float*)d_in[0];
    const float* Wp    = (const float*)d_in[1];
    const float* bp    = (const float*)d_in[2];
    const float* q_rot = (const float*)d_in[3];
    const float* k_rot = (const float*)d_in[4];
    const float* v_rot = (const float*)d_in[5];
    const float* ffr   = (const float*)d_in[6];
    const float* ffi   = (const float*)d_in[7];
    const float* Wr    = (const float*)d_in[8];
    const float* br    = (const float*)d_in[9];
    const float* Wi    = (const float*)d_in[10];
    const float* bi    = (const float*)d_in[11];
    float* out = (float*)d_out;

    float* ws = (float*)d_ws;
    const size_t plane = (size_t)MTOT * DD;      // 16,777,216 floats
    const size_t sline = (size_t)PP * DD;

    float* freq = ws;                  // 512
    float* cd   = freq + DD;
    float* sd   = cd + DD;
    float* cv   = sd + DD;
    float* sv   = cv + DD;
    int*   active = (int*)(sv + DD);   // 1
    float* Pr = ws + 4096;             // 65536
    float* Pi = Pr + (size_t)BB * DD;  // 65536
    float* part = Pi + (size_t)BB * DD;        // 2*NSLOT = 16384 floats
    float* Sr = part + 2 * NSLOT;              // fp32 state (128 MiB)
    float* Si = Sr + plane;
    unsigned short* Bt3 = (unsigned short*)(Si + plane);  // 1024x3072 bf16 (6 MB)
    float* chunkbase = Si + plane + (size_t)NK * KB / 2;

    const size_t fixed_f = (4096 + 2 * (size_t)BB * DD + 2 * NSLOT) + 2 * plane + (size_t)NK * KB / 2;
    // per-sample: U (PP*NK f32) + A2/X overlay (PP*KA bf16) + Y (PP*KA bf16) = 786432 floats = 3 MB
    const size_t perC_f = (size_t)PP * NK + (size_t)PP * KA;   // 786432

    // R9-proven power-of-2 chunking.
    int C = BB;
    while (C > 1 && (fixed_f + (size_t)C * perC_f) * 4ull > ws_size) C >>= 1;

    float* U = chunkbase;                                   // C x 256 x 1024 fp32
    float* Asc = U;                                         // overlay; dead before U written
    unsigned short* A2 = (unsigned short*)(U + (size_t)C * PP * NK);  // C x 256 x 2048 bf16
    unsigned short* X  = A2;                                // overlay: X dead before attnout writes A2
    unsigned short* Y  = A2 + (size_t)C * PP * KA;          // C x 256 x 2048 bf16

    k_setup<<<1, 512, 0, stream>>>(q_rot, k_rot, v_rot, freq, cd, sd, cv, sv, active);
    k_prep3<<<NK, 256, 0, stream>>>(ffr, ffi, Bt3);
    k_init<<<dim3(DD / 64, MTOT / 64), 256, 0, stream>>>(x, Wp, bp, freq, Sr, Si);

    for (int it = 0; it < 4; ++it) {
        for (int c0 = 0; c0 < BB; c0 += C) {
            float* Sr_c = Sr + (size_t)c0 * sline;
            float* Si_c = Si + (size_t)c0 * sline;
            float* part_c = part + (size_t)c0 * (PP / 4) * 2;
            k_xy<<<C * PP, 256, 0, stream>>>(Sr_c, Si_c, cd, sd, X, Y, active);
            k_score_mfma<<<dim3(2, C * 2), 256, 0, stream>>>(X, Y, Asc, active);
            k_softmax<<<C * PP / 4, 256, 0, stream>>>(Asc, active);
            k_attnout<<<dim3(DD / 64, PP / 64, C), 256, 0, stream>>>(Asc, Sr_c, Si_c, cv, sv, A2, active);
            k_ff_mfma3<<<dim3(NK / 128, C * 2), 256, 0, stream>>>(A2, Bt3, U, active);
            k_norm<<<C * (PP / 4), 256, 0, stream>>>(U, Sr_c, Si_c, part_c, active);
        }
        k_flag<<<1, 256, 0, stream>>>(part, active);
    }

    k_pool<<<BB * DD / 256, 256, 0, stream>>>(Sr, Si, Pr, Pi);
    k_logits<<<BB, 64, 0, stream>>>(Pr, Pi, Wr, br, Wi, bi, out);
}